// Round 11
// baseline (244.614 us; speedup 1.0000x reference)
//
#include <hip/hip_runtime.h>
#include <hip/hip_bf16.h>

typedef __bf16 bf16_8  __attribute__((ext_vector_type(8)));
typedef __bf16 bf16_4  __attribute__((ext_vector_type(4)));
typedef float  f32_4   __attribute__((ext_vector_type(4)));

#define NH 16
#define DHD 64
#define BB 2
#define SS 2048
#define DD 1024

// async global->LDS, 16B per lane; LDS dest must be wave-uniform base + lane*16
__device__ __forceinline__ void gload16(const __bf16* g, __bf16* l) {
    __builtin_amdgcn_global_load_lds(
        (const __attribute__((address_space(1))) void*)g,
        (__attribute__((address_space(3))) void*)l, 16, 0, 0);
}

// ---------------------------------------------------------------------------
// merged: f32 -> bf16 conversions (y<6) + mask tile flags (y=6,7).
// ---------------------------------------------------------------------------
__global__ __launch_bounds__(256) void conv_mask(
    const float* __restrict__ s0, const float* __restrict__ s1,
    const float* __restrict__ s2, const float* __restrict__ s3,
    const float* __restrict__ s4, const float* __restrict__ s5,
    __bf16* __restrict__ d0, __bf16* __restrict__ d1, __bf16* __restrict__ d2,
    __bf16* __restrict__ d3, __bf16* __restrict__ d4, __bf16* __restrict__ d5,
    const int* __restrict__ mask, int* __restrict__ flags) {
    const int y = blockIdx.y;
    if (y >= 6) {
        // ---- mask summary: flag[b][qt64][kt64] = any zero in 64x64 tile ----
        if (blockIdx.x >= 1024) return;
        const int id = (y - 6) * 1024 + blockIdx.x;  // b*1024 + qt*32 + kt
        const int b = id >> 10, qt = (id >> 5) & 31, kt = id & 31;
        const int t = threadIdx.x;
        const int row = t >> 2, seg = t & 3;
        const int* p = mask + ((size_t)b * SS + qt * 64 + row) * SS + kt * 64 + seg * 16;
        int any0 = 0;
#pragma unroll
        for (int i = 0; i < 4; ++i) {
            int4 v = *(const int4*)&p[i * 4];
            any0 |= (v.x == 0) | (v.y == 0) | (v.z == 0) | (v.w == 0);
        }
        unsigned long long bal = __ballot(any0);
        __shared__ int sf[4];
        if ((t & 63) == 0) sf[t >> 6] = (bal != 0ULL);
        __syncthreads();
        if (t == 0) flags[id] = sf[0] | sf[1] | sf[2] | sf[3];
        return;
    }
    if (y >= 2 && blockIdx.x >= 1024) return;
    const float* s = (y == 0) ? s0 : (y == 1) ? s1 : (y == 2) ? s2
                   : (y == 3) ? s3 : (y == 4) ? s4 : s5;
    __bf16* d      = (y == 0) ? d0 : (y == 1) ? d1 : (y == 2) ? d2
                   : (y == 3) ? d3 : (y == 4) ? d4 : d5;
    const int i = (blockIdx.x * 256 + threadIdx.x) * 4;
    f32_4 v = *(const f32_4*)&s[i];
    bf16_4 o; o[0] = (__bf16)v[0]; o[1] = (__bf16)v[1];
    o[2] = (__bf16)v[2]; o[3] = (__bf16)v[3];
    *(bf16_4*)&d[i] = o;
}

// ---------------------------------------------------------------------------
// QKV GEMM, C = A * W^T + bias. 128x64 tile, 6 blocks/CU, LINEAR dispatch
// (R9 lesson: n-major XCD swizzle doubled FETCH 37->69MB with ZERO time
// change -- linear dispatch already gives each XCD 4 m-tiles x all n, the
// right A-locality; and time is insensitive to memory placement anyway:
// the kernel sits at the documented m97-family 2-phase structure ceiling).
// K-loop: R5 dbuf; epilogue: R7 LDS-transpose wide stores.
// LAYOUT 0: (b,h,s,dh);  LAYOUT 2: V^T (b,h,dh,s).
// ---------------------------------------------------------------------------
template <int LAYOUT>
__device__ __forceinline__ void gemm_body(const __bf16* __restrict__ A,
                                          const __bf16* __restrict__ W,
                                          const float* __restrict__ bias,
                                          __bf16* __restrict__ out,
                                          __bf16* smem, int m0, int n0) {
    __bf16* ldsA0 = smem;             // 128*32 = 4096
    __bf16* ldsB0 = smem + 4096;      //  64*32 = 2048
    __bf16* ldsA1 = smem + 6144;      // 4096
    __bf16* ldsB1 = smem + 10240;     // 2048  (staging total 12288 elems = 24 KB)
    __bf16* ldsC  = smem;             // epilogue union: L0 128*72=9216, L2 64*136=8704

    const int tid  = threadIdx.x;
    const int lane = tid & 63;
    const int w    = tid >> 6;
    const int quad = lane >> 4;
    const int l15  = lane & 15;
    const int wm   = w * 32;

    f32_4 acc[2][4] = {};

    // 3 gload16/thread/tile: 2 A + 1 B
#define QSTAGE(KT, LA, LB)                                                     \
    do {                                                                       \
        _Pragma("unroll") for (int cc = 0; cc < 2; ++cc) {                     \
            const int c   = tid + cc * 256;                                    \
            const int row = c >> 2;                                            \
            const int cp  = c & 3;                                             \
            gload16(&A[(size_t)(m0 + row) * 1024 + (KT) + cp * 8],             \
                    &(LA)[c * 8]);                                             \
        }                                                                      \
        {                                                                      \
            const int c   = tid;                                               \
            const int row = c >> 2;                                            \
            const int cp  = c & 3;                                             \
            gload16(&W[(size_t)(n0 + row) * 1024 + (KT) + cp * 8],             \
                    &(LB)[c * 8]);                                             \
        }                                                                      \
    } while (0)

    QSTAGE(0, ldsA0, ldsB0);
    __syncthreads();  // tile 0 landed

    for (int kt = 0; kt < 1024; kt += 32) {
        const int sel = (kt >> 5) & 1;
        const __bf16* la = sel ? ldsA1 : ldsA0;
        const __bf16* lb = sel ? ldsB1 : ldsB0;
        __bf16* na       = sel ? ldsA0 : ldsA1;
        __bf16* nb       = sel ? ldsB0 : ldsB1;
        if (kt + 32 < 1024) QSTAGE(kt + 32, na, nb);  // async, overlaps MFMA

        bf16_8 af[2], bfr[4];
#pragma unroll
        for (int i = 0; i < 2; ++i)
            af[i] = *(const bf16_8*)&la[(wm + i * 16 + l15) * 32 + quad * 8];
#pragma unroll
        for (int j = 0; j < 4; ++j)
            bfr[j] = *(const bf16_8*)&lb[(j * 16 + l15) * 32 + quad * 8];
#pragma unroll
        for (int i = 0; i < 2; ++i)
#pragma unroll
            for (int j = 0; j < 4; ++j)
                acc[i][j] = __builtin_amdgcn_mfma_f32_16x16x32_bf16(
                    af[i], bfr[j], acc[i][j], 0, 0, 0);

        __syncthreads();  // prefetch landed; la/lb reads done before overwrite
    }
#undef QSTAGE

    // ---- epilogue: acc -> ldsC -> wide coalesced stores ----
    if (LAYOUT == 2) {
        // transposed LDS: ldsC[col][row] so acc r-quads pack into b64 writes
#pragma unroll
        for (int i = 0; i < 2; ++i)
#pragma unroll
            for (int j = 0; j < 4; ++j) {
                const int col = n0 + j * 16 + l15;
                const float bv = bias[col];
                bf16_4 pk;
#pragma unroll
                for (int r = 0; r < 4; ++r) pk[r] = (__bf16)(acc[i][j][r] + bv);
                *(bf16_4*)&ldsC[(j * 16 + l15) * 136 + wm + i * 16 + quad * 4] = pk;
            }
        __syncthreads();
#pragma unroll
        for (int it = 0; it < 4; ++it) {
            const int g    = it * 256 + tid;
            const int colp = g >> 4;         // 0..63 (dh-dim)
            const int s8   = (g & 15) * 8;   // 0..120 (s-dim)
            bf16_8 v = *(const bf16_8*)&ldsC[colp * 136 + s8];
            const int gcol = n0 + colp;
            const int grow = m0 + s8;
            *(bf16_8*)&out[(((size_t)(grow >> 11) * NH + (gcol >> 6)) * DHD +
                            (gcol & 63)) * SS + (grow & 2047)] = v;
        }
    } else {
        // row-major LDS: ldsC[row][col]
#pragma unroll
        for (int i = 0; i < 2; ++i)
#pragma unroll
            for (int j = 0; j < 4; ++j) {
                const int col = n0 + j * 16 + l15;
                const float bv = bias[col];
#pragma unroll
                for (int r = 0; r < 4; ++r)
                    ldsC[(wm + i * 16 + quad * 4 + r) * 72 + j * 16 + l15] =
                        (__bf16)(acc[i][j][r] + bv);
            }
        __syncthreads();
#pragma unroll
        for (int it = 0; it < 4; ++it) {
            const int g   = it * 256 + tid;
            const int row = g >> 3;          // 0..127
            const int c8  = (g & 7) * 8;     // 0..56
            bf16_8 v = *(const bf16_8*)&ldsC[row * 72 + c8];
            const int grow = m0 + row;
            const int gcol = n0 + c8;
            *(bf16_8*)&out[(((size_t)(grow >> 11) * NH + (gcol >> 6)) * SS +
                            (grow & 2047)) * DHD + (gcol & 63)] = v;
        }
    }
}

__global__ __launch_bounds__(256) void gemm_qkv(
    const __bf16* __restrict__ Xq, const __bf16* __restrict__ Xkv,
    const __bf16* __restrict__ Wq, const float* __restrict__ bq,
    const __bf16* __restrict__ Wk, const float* __restrict__ bk,
    const __bf16* __restrict__ Wv, const float* __restrict__ bv,
    __bf16* __restrict__ Qo, __bf16* __restrict__ Ko, __bf16* __restrict__ VTo) {
    __shared__ __align__(16) __bf16 smem[12288];  // 24 KB (staging+epilogue union)
    const int z = blockIdx.z;
    const __bf16* A    = (z == 0) ? Xq : Xkv;
    const __bf16* W    = (z == 0) ? Wq : (z == 1 ? Wk : Wv);
    const float* bias  = (z == 0) ? bq : (z == 1 ? bk : bv);
    if (z == 2)
        gemm_body<2>(A, W, bias, VTo, smem, blockIdx.x * 128, blockIdx.y * 64);
    else
        gemm_body<0>(A, W, bias, (z == 0) ? Qo : Ko, smem,
                     blockIdx.x * 128, blockIdx.y * 64);
}

// ---------------------------------------------------------------------------
// Final projection: 128x64 tile, BK=32, grid 512 (2/CU), LINEAR dispatch
// (swizzle reverted per R9 lesson), R5 dbuf loop + LDS-transpose epilogue.
// ---------------------------------------------------------------------------
__global__ __launch_bounds__(256) void gemm_final(
    const __bf16* __restrict__ A, const __bf16* __restrict__ W,
    const float* __restrict__ bias, float* __restrict__ out) {
    __shared__ __align__(16) float smemf[128 * 68];  // 34.8 KB union
    __bf16* ldsA0 = (__bf16*)smemf;          // 128*32 = 4096
    __bf16* ldsB0 = (__bf16*)smemf + 4096;   // 64*32  = 2048
    __bf16* ldsA1 = (__bf16*)smemf + 6144;
    __bf16* ldsB1 = (__bf16*)smemf + 10240;  // staging total 12288 elems (24 KB)
    float*  ldsC  = smemf;                   // epilogue reuse: 128*68 f32

    const int tid  = threadIdx.x;
    const int lane = tid & 63;
    const int w    = tid >> 6;
    const int quad = lane >> 4;
    const int l15  = lane & 15;
    const int wm   = w * 32;
    const int m0   = blockIdx.x * 128;
    const int n0   = blockIdx.y * 64;

    f32_4 acc[2][4] = {};

#define FSTAGE(KT, LA, LB)                                                     \
    do {                                                                       \
        _Pragma("unroll") for (int cc = 0; cc < 2; ++cc) {                     \
            const int c   = tid + cc * 256;                                    \
            const int row = c >> 2;                                            \
            const int cp  = c & 3;                                             \
            gload16(&A[(size_t)(m0 + row) * 1024 + (KT) + cp * 8],             \
                    &(LA)[c * 8]);                                             \
        }                                                                      \
        {                                                                      \
            const int c   = tid;                                               \
            const int row = c >> 2;                                            \
            const int cp  = c & 3;                                             \
            gload16(&W[(size_t)(n0 + row) * 1024 + (KT) + cp * 8],             \
                    &(LB)[c * 8]);                                             \
        }                                                                      \
    } while (0)

    FSTAGE(0, ldsA0, ldsB0);
    __syncthreads();

    for (int kt = 0; kt < 1024; kt += 32) {
        const int sel = (kt >> 5) & 1;
        const __bf16* la = sel ? ldsA1 : ldsA0;
        const __bf16* lb = sel ? ldsB1 : ldsB0;
        __bf16* na       = sel ? ldsA0 : ldsA1;
        __bf16* nb       = sel ? ldsB0 : ldsB1;
        if (kt + 32 < 1024) FSTAGE(kt + 32, na, nb);

        bf16_8 af[2], bfr[4];
#pragma unroll
        for (int i = 0; i < 2; ++i)
            af[i] = *(const bf16_8*)&la[(wm + i * 16 + l15) * 32 + quad * 8];
#pragma unroll
        for (int j = 0; j < 4; ++j)
            bfr[j] = *(const bf16_8*)&lb[(j * 16 + l15) * 32 + quad * 8];
#pragma unroll
        for (int i = 0; i < 2; ++i)
#pragma unroll
            for (int j = 0; j < 4; ++j)
                acc[i][j] = __builtin_amdgcn_mfma_f32_16x16x32_bf16(
                    af[i], bfr[j], acc[i][j], 0, 0, 0);

        __syncthreads();
    }
#undef FSTAGE

    // ---- epilogue: acc -> ldsC f32 -> f32_4 coalesced stores ----
#pragma unroll
    for (int i = 0; i < 2; ++i)
#pragma unroll
        for (int j = 0; j < 4; ++j) {
            const int col = n0 + j * 16 + l15;
            const float bv = bias[col];
#pragma unroll
            for (int r = 0; r < 4; ++r)
                ldsC[(wm + i * 16 + quad * 4 + r) * 68 + j * 16 + l15] =
                    acc[i][j][r] + bv;
        }
    __syncthreads();
#pragma unroll
    for (int it = 0; it < 8; ++it) {
        const int g   = it * 256 + tid;
        const int row = g >> 4;          // 0..127
        const int c4  = (g & 15) * 4;    // 0..60
        f32_4 v = *(const f32_4*)&ldsC[row * 68 + c4];
        *(f32_4*)&out[(size_t)(m0 + row) * 1024 + n0 + c4] = v;
    }
}

// ---------------------------------------------------------------------------
// Flash attention v11: q-tile 64 (was 128) -> grid 1024 blocks, 3 blocks/CU
// (LDS 41KB: K/V dbuf 32KB + SINGLE P[64][68] 8.5KB). R8 evidence:
// independent-block TLP is the knob that helps these barrier-stepped
// kernels (same-block waves don't, R1). Per-step serial chain (8 QKT MFMA,
// 16 exp, 10 PV MFMA) halves; 1.5x block overlap. Single-P safety: P rows
// are wave-private and the DS pipe is in-order per wave, so PV's reads of
// P(t) are serviced before EXPW's overwriting writes of P(t+1) (same-wave
// WAR) -- no extra wait, and the two barriers/iter already order staging.
// Pipeline unchanged otherwise: QK^T(t+1) || PV(t), ones-column row-sums,
// raw v_exp_f32, XCD swizzle (each XCD owns 4 bh-groups, K/V 2MB L2-fit).
// ---------------------------------------------------------------------------
__global__ __launch_bounds__(256, 3) void flash_attn(
    const __bf16* __restrict__ Q, const __bf16* __restrict__ K,
    const __bf16* __restrict__ VT, const int* __restrict__ mask,
    const int* __restrict__ flags, __bf16* __restrict__ O) {
    __shared__ __align__(16) __bf16 ldsK0[64 * 64];
    __shared__ __align__(16) __bf16 ldsK1[64 * 64];
    __shared__ __align__(16) __bf16 ldsV0[64 * 64];
    __shared__ __align__(16) __bf16 ldsV1[64 * 64];
    __shared__ __align__(16) __bf16 ldsP[64 * 68];

    const int tid  = threadIdx.x;
    const int lane = tid & 63;
    const int w    = tid >> 6;   // 0..3, wave owns q rows [w*16, w*16+16)
    const int quad = lane >> 4;
    const int l15  = lane & 15;
    // XCD swizzle: nwg=1024 -> l=(p&7)*128+p/8; XCD owns 4 full bh-groups
    // (K/V 4x512KB = 2MB, L2-resident) x all 32 q-blocks.
    const int p   = blockIdx.x + 32 * blockIdx.y;
    const int lg  = (p & 7) * 128 + (p >> 3);
    const int qx  = lg & 31;         // q-tile (64 rows)
    const int bh  = lg >> 5;
    const int q0  = qx * 64;
    const int b   = bh >> 4;

    const __bf16* Qb  = Q + (size_t)bh * SS * DHD;
    const __bf16* Kb  = K + (size_t)bh * SS * DHD;
    const __bf16* VTb = VT + (size_t)bh * DHD * SS;
    const int*    mb  = mask + (size_t)b * SS * SS;
    const int*    flb = flags + (size_t)b * 1024 + qx * 32;  // one 64-row flag row

    // Q fragments (B-operand of swapped QK^T), pre-scaled by 0.125*log2(e)
    bf16_8 qa[2];
#pragma unroll
    for (int ks = 0; ks < 2; ++ks) {
        bf16_8 t = *(const bf16_8*)&Qb[(size_t)(q0 + w * 16 + l15) * DHD +
                                       ks * 32 + quad * 8];
#pragma unroll
        for (int e = 0; e < 8; ++e)
            qa[ks][e] = (__bf16)((float)t[e] * 0.18033688011112042f);
    }

    bf16_8 ones;
#pragma unroll
    for (int e = 0; e < 8; ++e) ones[e] = (__bf16)1.0f;

    f32_4 of[4] = {};
    f32_4 lsum = {};

    // staging geometry: 512 16B-chunks per buffer over 256 threads (2 each);
    // chunk c -> row=c>>3, 16B-group g=c&7; global source group = g ^ (row&7)
    const int c0 = tid, c1 = tid + 256;
    const int r_0 = c0 >> 3, r_1 = c1 >> 3;
    const int s_0 = (c0 & 7) ^ (r_0 & 7);
    const int s_1 = (c1 & 7) ^ (r_1 & 7);

#define STAGE_K(K0_, DST)                                                      \
    do {                                                                       \
        gload16(&Kb[(size_t)((K0_) + r_0) * DHD + s_0 * 8], &(DST)[c0 * 8]);   \
        gload16(&Kb[(size_t)((K0_) + r_1) * DHD + s_1 * 8], &(DST)[c1 * 8]);   \
    } while (0)
#define STAGE_V(K0_, DST)                                                      \
    do {                                                                       \
        gload16(&VTb[(size_t)r_0 * SS + (K0_) + s_0 * 8], &(DST)[c0 * 8]);     \
        gload16(&VTb[(size_t)r_1 * SS + (K0_) + s_1 * 8], &(DST)[c1 * 8]);     \
    } while (0)

    const int xq = l15 & 7;  // read-side swizzle key

    // QK^T of one 64-wide k-tile: sa[j] = S^T, lane = S[q=l15][k=j*16+quad*4+r]
#define QKT(KSRC, SA)                                                          \
    do {                                                                       \
        _Pragma("unroll") for (int ks = 0; ks < 2; ++ks) {                     \
            bf16_8 kb[4];                                                      \
            _Pragma("unroll") for (int j = 0; j < 4; ++j)                      \
                kb[j] = *(const bf16_8*)&(KSRC)[(j * 16 + l15) * 64 +          \
                                                (((ks * 4 + quad) ^ xq) * 8)]; \
            _Pragma("unroll") for (int j = 0; j < 4; ++j)                      \
                SA[j] = __builtin_amdgcn_mfma_f32_16x16x32_bf16(               \
                    kb[j], qa[ks], SA[j], 0, 0, 0);                            \
        }                                                                      \
    } while (0)

#define MASKF(TN, SA)                                                          \
    do {                                                                       \
        if (flb[TN] != 0) {                                                    \
            _Pragma("unroll") for (int j = 0; j < 4; ++j)                      \
                _Pragma("unroll") for (int r = 0; r < 4; ++r) {                \
                    const int qg = q0 + w * 16 + l15;                          \
                    const int kg = (TN) * 64 + j * 16 + quad * 4 + r;          \
                    if (mb[(size_t)qg * SS + kg] == 0) SA[j][r] = -1e9f;       \
                }                                                              \
        }                                                                      \
    } while (0)

#define EXPW(SA)                                                               \
    do {                                                                       \
        _Pragma("unroll") for (int j = 0; j < 4; ++j) {                        \
            bf16_4 pk;                                                         \
            _Pragma("unroll") for (int r = 0; r < 4; ++r)                      \
                pk[r] = (__bf16)__builtin_amdgcn_exp2f(SA[j][r]);              \
            *(bf16_4*)&ldsP[(w * 16 + l15) * 68 + j * 16 + quad * 4] = pk;     \
        }                                                                      \
    } while (0)

#define PV(VSRC)                                                               \
    do {                                                                       \
        _Pragma("unroll") for (int ks2 = 0; ks2 < 2; ++ks2) {                  \
            bf16_8 pa, vb[4];                                                  \
            pa = *(const bf16_8*)&ldsP[(w * 16 + l15) * 68 + ks2 * 32 +        \
                                       quad * 8];                              \
            _Pragma("unroll") for (int jo = 0; jo < 4; ++jo)                   \
                vb[jo] = *(const bf16_8*)&(VSRC)[(jo * 16 + l15) * 64 +        \
                                                 (((ks2 * 4 + quad) ^ xq) * 8)]; \
            __builtin_amdgcn_s_setprio(1);                                     \
            _Pragma("unroll") for (int jo = 0; jo < 4; ++jo)                   \
                of[jo] = __builtin_amdgcn_mfma_f32_16x16x32_bf16(              \
                    pa, vb[jo], of[jo], 0, 0, 0);                              \
            lsum = __builtin_amdgcn_mfma_f32_16x16x32_bf16(                    \
                pa, ones, lsum, 0, 0, 0);                                      \
            __builtin_amdgcn_s_setprio(0);                                     \
        }                                                                      \
    } while (0)

    // ---- prologue: tile 0 staged, QK^T(0)+exp(0) -> P; tile 1 staging ----
    STAGE_K(0, ldsK0);
    STAGE_V(0, ldsV0);
    __syncthreads();  // tile 0 landed
    STAGE_K(64, ldsK1);
    STAGE_V(64, ldsV1);
    {
        f32_4 sa[4] = {};
        QKT(ldsK0, sa);
        MASKF(0, sa);
        EXPW(sa);       // P(0)
    }
    __syncthreads();  // tile 1 landed

    // ---- main loop: iter t does QK^T(t+1) + PV(t) ----
    for (int t = 0; t < 31; ++t) {
        const int sel = t & 1;
        __bf16* kst       = sel ? ldsK1 : ldsK0;  // stage K(t+2) here
        const __bf16* kn  = sel ? ldsK0 : ldsK1;  // K(t+1)
        const __bf16* vc  = sel ? ldsV1 : ldsV0;  // V(t)
        __bf16* vst       = sel ? ldsV1 : ldsV0;  // stage V(t+2) (after barrier)

        if (t < 30) STAGE_K((t + 2) * 64, kst);

        f32_4 sa[4] = {};
        QKT(kn, sa);        // tile t+1
        MASKF(t + 1, sa);
        PV(vc);             // tile t: reads P(t) (in-order DS, before EXPW writes)
        EXPW(sa);           // writes P(t+1): same-wave WAR via in-order DS pipe

        __syncthreads();    // staged K landed; all waves done reading vc/kn
        if (t < 30) STAGE_V((t + 2) * 64, vst);
    }

    // ---- epilogue: PV(31) ----
    PV(ldsV1);

    // normalize + store: lsum[r] is the row-sum for exactly the q-row
    // of[jo][r] holds (col l15 copies are identical) -> no shuffles.
    const int hcol = (bh & 15) * 64;
#pragma unroll
    for (int r = 0; r < 4; ++r) {
        const float inv = 1.0f / fmaxf(lsum[r], 1e-37f);
        const int qg = q0 + w * 16 + quad * 4 + r;
#pragma unroll
        for (int jo = 0; jo < 4; ++jo)
            O[((size_t)b * SS + qg) * DD + hcol + jo * 16 + l15] =
                (__bf16)(of[jo][r] * inv);
    }
#undef STAGE_K
#undef STAGE_V
#undef QKT
#undef MASKF
#undef EXPW
#undef PV
}

// ---------------------------------------------------------------------------

extern "C" void kernel_launch(void* const* d_in, const int* in_sizes, int n_in,
                              void* d_out, int out_size, void* d_ws, size_t ws_size,
                              hipStream_t stream) {
    const float* xq   = (const float*)d_in[0];
    const float* xkv  = (const float*)d_in[1];
    const int*   mask = (const int*)d_in[2];
    const float* Wq   = (const float*)d_in[3];
    const float* bq   = (const float*)d_in[4];
    const float* Wk   = (const float*)d_in[5];
    const float* bk   = (const float*)d_in[6];
    const float* Wv   = (const float*)d_in[7];
    const float* bv   = (const float*)d_in[8];
    const float* Wo   = (const float*)d_in[9];
    const float* bo   = (const float*)d_in[10];

    __bf16* ws = (__bf16*)d_ws;
    const size_t big = (size_t)BB * SS * DD;  // 4,194,304
    const size_t wsz = (size_t)DD * DD;       // 1,048,576
    __bf16* Qw   = ws;
    __bf16* Kw   = Qw + big;
    __bf16* VTw  = Kw + big;
    __bf16* Aw   = VTw + big;
    __bf16* Xqb  = Aw + big;
    __bf16* Xkvb = Xqb + big;
    __bf16* Wqb  = Xkvb + big;
    __bf16* Wkb  = Wqb + wsz;
    __bf16* Wvb  = Wkb + wsz;
    __bf16* Wob  = Wvb + wsz;
    int* flags   = (int*)(Wob + wsz);  // 2048 ints

    conv_mask<<<dim3(4096, 8), dim3(256), 0, stream>>>(xq, xkv, Wq, Wk, Wv, Wo,
                                                       Xqb, Xkvb, Wqb, Wkb, Wvb, Wob,
                                                       mask, flags);
    gemm_qkv<<<dim3(32, 16, 3), dim3(256), 0, stream>>>(Xqb, Xkvb, Wqb, bq, Wkb, bk,
                                                        Wvb, bv, Qw, Kw, VTw);
    flash_attn<<<dim3(32, 32), dim3(256), 0, stream>>>(Qw, Kw, VTw, mask,
                                                       flags, Aw);
    gemm_final<<<dim3(32, 16), dim3(256), 0, stream>>>(Aw, Wob, bo, (float*)d_out);
}

// Round 12
// 220.056 us; speedup vs baseline: 1.1116x; 1.1116x over previous
//
#include <hip/hip_runtime.h>
#include <hip/hip_bf16.h>

typedef __bf16 bf16_8  __attribute__((ext_vector_type(8)));
typedef __bf16 bf16_4  __attribute__((ext_vector_type(4)));
typedef float  f32_4   __attribute__((ext_vector_type(4)));

#define NH 16
#define DHD 64
#define BB 2
#define SS 2048
#define DD 1024

// async global->LDS, 16B per lane; LDS dest must be wave-uniform base + lane*16
__device__ __forceinline__ void gload16(const __bf16* g, __bf16* l) {
    __builtin_amdgcn_global_load_lds(
        (const __attribute__((address_space(1))) void*)g,
        (__attribute__((address_space(3))) void*)l, 16, 0, 0);
}

// ---------------------------------------------------------------------------
// merged: f32 -> bf16 conversions (y<6) + mask tile flags (y=6,7).
// ---------------------------------------------------------------------------
__global__ __launch_bounds__(256) void conv_mask(
    const float* __restrict__ s0, const float* __restrict__ s1,
    const float* __restrict__ s2, const float* __restrict__ s3,
    const float* __restrict__ s4, const float* __restrict__ s5,
    __bf16* __restrict__ d0, __bf16* __restrict__ d1, __bf16* __restrict__ d2,
    __bf16* __restrict__ d3, __bf16* __restrict__ d4, __bf16* __restrict__ d5,
    const int* __restrict__ mask, int* __restrict__ flags) {
    const int y = blockIdx.y;
    if (y >= 6) {
        // ---- mask summary: flag[b][qt64][kt64] = any zero in 64x64 tile ----
        if (blockIdx.x >= 1024) return;
        const int id = (y - 6) * 1024 + blockIdx.x;  // b*1024 + qt*32 + kt
        const int b = id >> 10, qt = (id >> 5) & 31, kt = id & 31;
        const int t = threadIdx.x;
        const int row = t >> 2, seg = t & 3;
        const int* p = mask + ((size_t)b * SS + qt * 64 + row) * SS + kt * 64 + seg * 16;
        int any0 = 0;
#pragma unroll
        for (int i = 0; i < 4; ++i) {
            int4 v = *(const int4*)&p[i * 4];
            any0 |= (v.x == 0) | (v.y == 0) | (v.z == 0) | (v.w == 0);
        }
        unsigned long long bal = __ballot(any0);
        __shared__ int sf[4];
        if ((t & 63) == 0) sf[t >> 6] = (bal != 0ULL);
        __syncthreads();
        if (t == 0) flags[id] = sf[0] | sf[1] | sf[2] | sf[3];
        return;
    }
    if (y >= 2 && blockIdx.x >= 1024) return;
    const float* s = (y == 0) ? s0 : (y == 1) ? s1 : (y == 2) ? s2
                   : (y == 3) ? s3 : (y == 4) ? s4 : s5;
    __bf16* d      = (y == 0) ? d0 : (y == 1) ? d1 : (y == 2) ? d2
                   : (y == 3) ? d3 : (y == 4) ? d4 : d5;
    const int i = (blockIdx.x * 256 + threadIdx.x) * 4;
    f32_4 v = *(const f32_4*)&s[i];
    bf16_4 o; o[0] = (__bf16)v[0]; o[1] = (__bf16)v[1];
    o[2] = (__bf16)v[2]; o[3] = (__bf16)v[3];
    *(bf16_4*)&d[i] = o;
}

// ---------------------------------------------------------------------------
// QKV GEMM, C = A * W^T + bias. Round-12: BK 32->64 -- HALF the barrier/
// drain events per block (16 K-steps instead of 32). R11 falsified the
// locality/occupancy theories (flash: FETCH 70->12MB, conflicts->0, occ up,
// yet 17% SLOWER at 2x barrier-steps): the binding constraint is
// (#barrier-drain events) x (fixed drain cost). BK=64 keeps total work and
// staging bytes identical, halves the events. 128B LDS rows would be a
// 16-way b128 conflict (G4), so staging uses the flash-proven XOR swizzle:
// linear LDS dest + global source group ^(row&7) + same XOR on reads
// (rule 21; flash measured 0 conflicts with this). LDS 48KB -> 3 blk/CU
// (R7/R8: 3 vs 6 blk/CU near-neutral). Epilogue: R7 wide stores. LINEAR
// dispatch (R9: XCD swizzle doubled FETCH, zero time change).
// LAYOUT 0: (b,h,s,dh);  LAYOUT 2: V^T (b,h,dh,s).
// ---------------------------------------------------------------------------
template <int LAYOUT>
__device__ __forceinline__ void gemm_body(const __bf16* __restrict__ A,
                                          const __bf16* __restrict__ W,
                                          const float* __restrict__ bias,
                                          __bf16* __restrict__ out,
                                          __bf16* smem, int m0, int n0) {
    __bf16* ldsA0 = smem;             // 128*64 = 8192
    __bf16* ldsB0 = smem + 8192;      //  64*64 = 4096
    __bf16* ldsA1 = smem + 12288;     // 8192
    __bf16* ldsB1 = smem + 20480;     // 4096  (staging total 24576 elems = 48 KB)
    __bf16* ldsC  = smem;             // epilogue union: L0 128*72=9216, L2 64*136=8704

    const int tid  = threadIdx.x;
    const int lane = tid & 63;
    const int w    = tid >> 6;
    const int quad = lane >> 4;
    const int l15  = lane & 15;
    const int wm   = w * 32;
    const int xq   = l15 & 7;   // read-side swizzle key (rows l15 mod 8)

    f32_4 acc[2][4] = {};

    // 6 gload16/thread/tile: 4 A + 2 B; source 16B-group XOR'd by row&7
#define QSTAGE(KT, LA, LB)                                                     \
    do {                                                                       \
        _Pragma("unroll") for (int cc = 0; cc < 4; ++cc) {                     \
            const int c   = tid + cc * 256;                                    \
            const int row = c >> 3;                                            \
            const int sg  = (c & 7) ^ (row & 7);                               \
            gload16(&A[(size_t)(m0 + row) * 1024 + (KT) + sg * 8],             \
                    &(LA)[c * 8]);                                             \
        }                                                                      \
        _Pragma("unroll") for (int cc = 0; cc < 2; ++cc) {                     \
            const int c   = tid + cc * 256;                                    \
            const int row = c >> 3;                                            \
            const int sg  = (c & 7) ^ (row & 7);                               \
            gload16(&W[(size_t)(n0 + row) * 1024 + (KT) + sg * 8],             \
                    &(LB)[c * 8]);                                             \
        }                                                                      \
    } while (0)

    QSTAGE(0, ldsA0, ldsB0);
    __syncthreads();  // tile 0 landed

    for (int kt = 0; kt < 1024; kt += 64) {
        const int sel = (kt >> 6) & 1;
        const __bf16* la = sel ? ldsA1 : ldsA0;
        const __bf16* lb = sel ? ldsB1 : ldsB0;
        __bf16* na       = sel ? ldsA0 : ldsA1;
        __bf16* nb       = sel ? ldsB0 : ldsB1;
        if (kt + 64 < 1024) QSTAGE(kt + 64, na, nb);  // async, overlaps MFMA

#pragma unroll
        for (int ks = 0; ks < 2; ++ks) {
            bf16_8 af[2], bfr[4];
#pragma unroll
            for (int i = 0; i < 2; ++i)
                af[i] = *(const bf16_8*)&la[(wm + i * 16 + l15) * 64 +
                                            (((ks * 4 + quad) ^ xq) * 8)];
#pragma unroll
            for (int j = 0; j < 4; ++j)
                bfr[j] = *(const bf16_8*)&lb[(j * 16 + l15) * 64 +
                                             (((ks * 4 + quad) ^ xq) * 8)];
#pragma unroll
            for (int i = 0; i < 2; ++i)
#pragma unroll
                for (int j = 0; j < 4; ++j)
                    acc[i][j] = __builtin_amdgcn_mfma_f32_16x16x32_bf16(
                        af[i], bfr[j], acc[i][j], 0, 0, 0);
        }

        __syncthreads();  // prefetch landed; la/lb reads done before overwrite
    }
#undef QSTAGE

    // ---- epilogue: acc -> ldsC -> wide coalesced stores ----
    if (LAYOUT == 2) {
        // transposed LDS: ldsC[col][row] so acc r-quads pack into b64 writes
#pragma unroll
        for (int i = 0; i < 2; ++i)
#pragma unroll
            for (int j = 0; j < 4; ++j) {
                const int col = n0 + j * 16 + l15;
                const float bv = bias[col];
                bf16_4 pk;
#pragma unroll
                for (int r = 0; r < 4; ++r) pk[r] = (__bf16)(acc[i][j][r] + bv);
                *(bf16_4*)&ldsC[(j * 16 + l15) * 136 + wm + i * 16 + quad * 4] = pk;
            }
        __syncthreads();
#pragma unroll
        for (int it = 0; it < 4; ++it) {
            const int g    = it * 256 + tid;
            const int colp = g >> 4;         // 0..63 (dh-dim)
            const int s8   = (g & 15) * 8;   // 0..120 (s-dim)
            bf16_8 v = *(const bf16_8*)&ldsC[colp * 136 + s8];
            const int gcol = n0 + colp;
            const int grow = m0 + s8;
            *(bf16_8*)&out[(((size_t)(grow >> 11) * NH + (gcol >> 6)) * DHD +
                            (gcol & 63)) * SS + (grow & 2047)] = v;
        }
    } else {
        // row-major LDS: ldsC[row][col]
#pragma unroll
        for (int i = 0; i < 2; ++i)
#pragma unroll
            for (int j = 0; j < 4; ++j) {
                const int col = n0 + j * 16 + l15;
                const float bv = bias[col];
#pragma unroll
                for (int r = 0; r < 4; ++r)
                    ldsC[(wm + i * 16 + quad * 4 + r) * 72 + j * 16 + l15] =
                        (__bf16)(acc[i][j][r] + bv);
            }
        __syncthreads();
#pragma unroll
        for (int it = 0; it < 4; ++it) {
            const int g   = it * 256 + tid;
            const int row = g >> 3;          // 0..127
            const int c8  = (g & 7) * 8;     // 0..56
            bf16_8 v = *(const bf16_8*)&ldsC[row * 72 + c8];
            const int grow = m0 + row;
            const int gcol = n0 + c8;
            *(bf16_8*)&out[(((size_t)(grow >> 11) * NH + (gcol >> 6)) * SS +
                            (grow & 2047)) * DHD + (gcol & 63)] = v;
        }
    }
}

__global__ __launch_bounds__(256) void gemm_qkv(
    const __bf16* __restrict__ Xq, const __bf16* __restrict__ Xkv,
    const __bf16* __restrict__ Wq, const float* __restrict__ bq,
    const __bf16* __restrict__ Wk, const float* __restrict__ bk,
    const __bf16* __restrict__ Wv, const float* __restrict__ bv,
    __bf16* __restrict__ Qo, __bf16* __restrict__ Ko, __bf16* __restrict__ VTo) {
    __shared__ __align__(16) __bf16 smem[24576];  // 48 KB (staging+epilogue union)
    const int z = blockIdx.z;
    const __bf16* A    = (z == 0) ? Xq : Xkv;
    const __bf16* W    = (z == 0) ? Wq : (z == 1 ? Wk : Wv);
    const float* bias  = (z == 0) ? bq : (z == 1 ? bk : bv);
    if (z == 2)
        gemm_body<2>(A, W, bias, VTo, smem, blockIdx.x * 128, blockIdx.y * 64);
    else
        gemm_body<0>(A, W, bias, (z == 0) ? Qo : Ko, smem,
                     blockIdx.x * 128, blockIdx.y * 64);
}

// ---------------------------------------------------------------------------
// Final projection: 128x64 tile, BK=32, grid 512 (2/CU), LINEAR dispatch,
// R5 dbuf loop + LDS-transpose epilogue. (Unchanged -- attribution.)
// ---------------------------------------------------------------------------
__global__ __launch_bounds__(256) void gemm_final(
    const __bf16* __restrict__ A, const __bf16* __restrict__ W,
    const float* __restrict__ bias, float* __restrict__ out) {
    __shared__ __align__(16) float smemf[128 * 68];  // 34.8 KB union
    __bf16* ldsA0 = (__bf16*)smemf;          // 128*32 = 4096
    __bf16* ldsB0 = (__bf16*)smemf + 4096;   // 64*32  = 2048
    __bf16* ldsA1 = (__bf16*)smemf + 6144;
    __bf16* ldsB1 = (__bf16*)smemf + 10240;  // staging total 12288 elems (24 KB)
    float*  ldsC  = smemf;                   // epilogue reuse: 128*68 f32

    const int tid  = threadIdx.x;
    const int lane = tid & 63;
    const int w    = tid >> 6;
    const int quad = lane >> 4;
    const int l15  = lane & 15;
    const int wm   = w * 32;
    const int m0   = blockIdx.x * 128;
    const int n0   = blockIdx.y * 64;

    f32_4 acc[2][4] = {};

#define FSTAGE(KT, LA, LB)                                                     \
    do {                                                                       \
        _Pragma("unroll") for (int cc = 0; cc < 2; ++cc) {                     \
            const int c   = tid + cc * 256;                                    \
            const int row = c >> 2;                                            \
            const int cp  = c & 3;                                             \
            gload16(&A[(size_t)(m0 + row) * 1024 + (KT) + cp * 8],             \
                    &(LA)[c * 8]);                                             \
        }                                                                      \
        {                                                                      \
            const int c   = tid;                                               \
            const int row = c >> 2;                                            \
            const int cp  = c & 3;                                             \
            gload16(&W[(size_t)(n0 + row) * 1024 + (KT) + cp * 8],             \
                    &(LB)[c * 8]);                                             \
        }                                                                      \
    } while (0)

    FSTAGE(0, ldsA0, ldsB0);
    __syncthreads();

    for (int kt = 0; kt < 1024; kt += 32) {
        const int sel = (kt >> 5) & 1;
        const __bf16* la = sel ? ldsA1 : ldsA0;
        const __bf16* lb = sel ? ldsB1 : ldsB0;
        __bf16* na       = sel ? ldsA0 : ldsA1;
        __bf16* nb       = sel ? ldsB0 : ldsB1;
        if (kt + 32 < 1024) FSTAGE(kt + 32, na, nb);

        bf16_8 af[2], bfr[4];
#pragma unroll
        for (int i = 0; i < 2; ++i)
            af[i] = *(const bf16_8*)&la[(wm + i * 16 + l15) * 32 + quad * 8];
#pragma unroll
        for (int j = 0; j < 4; ++j)
            bfr[j] = *(const bf16_8*)&lb[(j * 16 + l15) * 32 + quad * 8];
#pragma unroll
        for (int i = 0; i < 2; ++i)
#pragma unroll
            for (int j = 0; j < 4; ++j)
                acc[i][j] = __builtin_amdgcn_mfma_f32_16x16x32_bf16(
                    af[i], bfr[j], acc[i][j], 0, 0, 0);

        __syncthreads();
    }
#undef FSTAGE

    // ---- epilogue: acc -> ldsC f32 -> f32_4 coalesced stores ----
#pragma unroll
    for (int i = 0; i < 2; ++i)
#pragma unroll
        for (int j = 0; j < 4; ++j) {
            const int col = n0 + j * 16 + l15;
            const float bv = bias[col];
#pragma unroll
            for (int r = 0; r < 4; ++r)
                ldsC[(wm + i * 16 + quad * 4 + r) * 68 + j * 16 + l15] =
                    acc[i][j][r] + bv;
        }
    __syncthreads();
#pragma unroll
    for (int it = 0; it < 8; ++it) {
        const int g   = it * 256 + tid;
        const int row = g >> 4;          // 0..127
        const int c4  = (g & 15) * 4;    // 0..60
        f32_4 v = *(const f32_4*)&ldsC[row * 68 + c4];
        *(f32_4*)&out[(size_t)(m0 + row) * 1024 + n0 + c4] = v;
    }
}

// ---------------------------------------------------------------------------
// Flash attention v9 (RESTORED from round 8 -- directly measured 51.0-52.0us
// there; R11's q-tile-64 variant regressed to 59.6 despite better locality/
// occupancy, proving barrier-event count is the binding constraint).
// 1-tile software pipeline (QK^T(t+1) || PV(t)), double-buffered P, one
// barrier/tile, ones-column MFMA row-sums, raw v_exp_f32.
// ---------------------------------------------------------------------------
__global__ __launch_bounds__(256, 2) void flash_attn(
    const __bf16* __restrict__ Q, const __bf16* __restrict__ K,
    const __bf16* __restrict__ VT, const int* __restrict__ mask,
    const int* __restrict__ flags, __bf16* __restrict__ O) {
    __shared__ __align__(16) __bf16 ldsK0[64 * 64];
    __shared__ __align__(16) __bf16 ldsK1[64 * 64];
    __shared__ __align__(16) __bf16 ldsV0[64 * 64];
    __shared__ __align__(16) __bf16 ldsV1[64 * 64];
    __shared__ __align__(16) __bf16 ldsP0[128 * 72];
    __shared__ __align__(16) __bf16 ldsP1[128 * 72];

    const int tid  = threadIdx.x;
    const int lane = tid & 63;
    const int w    = tid >> 6;   // 0..3
    const int quad = lane >> 4;
    const int l15  = lane & 15;
    const int q0   = blockIdx.x * 128;
    const int bh   = blockIdx.y;
    const int b    = bh >> 4;

    const __bf16* Qb  = Q + (size_t)bh * SS * DHD;
    const __bf16* Kb  = K + (size_t)bh * SS * DHD;
    const __bf16* VTb = VT + (size_t)bh * DHD * SS;
    const int*    mb  = mask + (size_t)b * SS * SS;
    const int*    flb = flags + (size_t)b * 1024 + blockIdx.x * 64;

    // Q fragments (B-operand of swapped QK^T), pre-scaled by 0.125*log2(e)
    bf16_8 qa[2][2];
#pragma unroll
    for (int mt = 0; mt < 2; ++mt)
#pragma unroll
        for (int ks = 0; ks < 2; ++ks) {
            bf16_8 t = *(const bf16_8*)&Qb[(size_t)(q0 + w * 32 + mt * 16 + l15) * DHD +
                                           ks * 32 + quad * 8];
#pragma unroll
            for (int e = 0; e < 8; ++e)
                qa[mt][ks][e] = (__bf16)((float)t[e] * 0.18033688011112042f);
        }

    bf16_8 ones;
#pragma unroll
    for (int e = 0; e < 8; ++e) ones[e] = (__bf16)1.0f;

    f32_4 of[2][4] = {};
    f32_4 lsum[2] = {};

    // staging geometry: 512 16B-chunks per buffer over 256 threads (2 each);
    // chunk c -> row=c>>3, 16B-group g=c&7; global source group = g ^ (row&7)
    const int c0 = tid, c1 = tid + 256;
    const int r_0 = c0 >> 3, r_1 = c1 >> 3;
    const int s_0 = (c0 & 7) ^ (r_0 & 7);
    const int s_1 = (c1 & 7) ^ (r_1 & 7);

#define STAGE_K(K0_, DST)                                                      \
    do {                                                                       \
        gload16(&Kb[(size_t)((K0_) + r_0) * DHD + s_0 * 8], &(DST)[c0 * 8]);   \
        gload16(&Kb[(size_t)((K0_) + r_1) * DHD + s_1 * 8], &(DST)[c1 * 8]);   \
    } while (0)
#define STAGE_V(K0_, DST)                                                      \
    do {                                                                       \
        gload16(&VTb[(size_t)r_0 * SS + (K0_) + s_0 * 8], &(DST)[c0 * 8]);     \
        gload16(&VTb[(size_t)r_1 * SS + (K0_) + s_1 * 8], &(DST)[c1 * 8]);     \
    } while (0)

    const int xq = l15 & 7;  // read-side swizzle key

    // QK^T of tile TN from KSRC -> sa (S^T: lane = S[q=l15][k=quad*4+r+j*16])
#define QKT(KSRC, SA)                                                          \
    do {                                                                       \
        _Pragma("unroll") for (int ks = 0; ks < 2; ++ks) {                     \
            bf16_8 kb[4];                                                      \
            _Pragma("unroll") for (int j = 0; j < 4; ++j)                      \
                kb[j] = *(const bf16_8*)&(KSRC)[(j * 16 + l15) * 64 +          \
                                                (((ks * 4 + quad) ^ xq) * 8)]; \
            _Pragma("unroll") for (int mt = 0; mt < 2; ++mt)                   \
                _Pragma("unroll") for (int j = 0; j < 4; ++j)                  \
                    SA[mt][j] = __builtin_amdgcn_mfma_f32_16x16x32_bf16(       \
                        kb[j], qa[mt][ks], SA[mt][j], 0, 0, 0);                \
        }                                                                      \
    } while (0)

#define MASKF(TN, SA)                                                          \
    do {                                                                       \
        if ((flb[TN] | flb[32 + (TN)]) != 0) {                                 \
            _Pragma("unroll") for (int mt = 0; mt < 2; ++mt)                   \
                _Pragma("unroll") for (int j = 0; j < 4; ++j)                  \
                    _Pragma("unroll") for (int r = 0; r < 4; ++r) {            \
                        const int qg = q0 + w * 32 + mt * 16 + l15;            \
                        const int kg = (TN) * 64 + j * 16 + quad * 4 + r;      \
                        if (mb[(size_t)qg * SS + kg] == 0) SA[mt][j][r] = -1e9f; \
                    }                                                          \
        }                                                                      \
    } while (0)

#define EXPW(SA, PDST)                                                         \
    do {                                                                       \
        _Pragma("unroll") for (int mt = 0; mt < 2; ++mt)                       \
            _Pragma("unroll") for (int j = 0; j < 4; ++j) {                    \
                bf16_4 pk;                                                     \
                _Pragma("unroll") for (int r = 0; r < 4; ++r)                  \
                    pk[r] = (__bf16)__builtin_amdgcn_exp2f(SA[mt][j][r]);      \
                *(bf16_4*)&(PDST)[(w * 32 + mt * 16 + l15) * 72 + j * 16 +     \
                                  quad * 4] = pk;                              \
            }                                                                  \
    } while (0)

#define PV(VSRC, PSRC)                                                         \
    do {                                                                       \
        _Pragma("unroll") for (int ks2 = 0; ks2 < 2; ++ks2) {                  \
            bf16_8 pa[2], vb[4];                                               \
            _Pragma("unroll") for (int mt = 0; mt < 2; ++mt)                   \
                pa[mt] = *(const bf16_8*)&(PSRC)[(w * 32 + mt * 16 + l15) * 72 \
                                                 + ks2 * 32 + quad * 8];       \
            _Pragma("unroll") for (int jo = 0; jo < 4; ++jo)                   \
                vb[jo] = *(const bf16_8*)&(VSRC)[(jo * 16 + l15) * 64 +        \
                                                 (((ks2 * 4 + quad) ^ xq) * 8)]; \
            __builtin_amdgcn_s_setprio(1);                                     \
            _Pragma("unroll") for (int mt = 0; mt < 2; ++mt) {                 \
                _Pragma("unroll") for (int jo = 0; jo < 4; ++jo)               \
                    of[mt][jo] = __builtin_amdgcn_mfma_f32_16x16x32_bf16(      \
                        pa[mt], vb[jo], of[mt][jo], 0, 0, 0);                  \
                lsum[mt] = __builtin_amdgcn_mfma_f32_16x16x32_bf16(            \
                    pa[mt], ones, lsum[mt], 0, 0, 0);                          \
            }                                                                  \
            __builtin_amdgcn_s_setprio(0);                                     \
        }                                                                      \
    } while (0)

    // ---- prologue: tile 0 staged, QK^T(0)+exp(0) -> P0; tile 1 staging ----
    STAGE_K(0, ldsK0);
    STAGE_V(0, ldsV0);
    __syncthreads();  // tile 0 landed
    STAGE_K(64, ldsK1);
    STAGE_V(64, ldsV1);
    {
        f32_4 sa[2][4] = {};
        QKT(ldsK0, sa);
        MASKF(0, sa);
        EXPW(sa, ldsP0);
    }
    __syncthreads();  // tile 1 landed; P0 visible

    // ---- main loop: iter t does QK^T(t+1) + PV(t) ----
    for (int t = 0; t < 31; ++t) {
        const int sel = t & 1;
        __bf16* kst       = sel ? ldsK1 : ldsK0;  // stage K(t+2) here
        const __bf16* kn  = sel ? ldsK0 : ldsK1;  // K(t+1)
        const __bf16* vc  = sel ? ldsV1 : ldsV0;  // V(t)
        const __bf16* pc  = sel ? ldsP1 : ldsP0;  // P(t)
        __bf16* pn        = sel ? ldsP0 : ldsP1;  // P(t+1)
        __bf16* vst       = sel ? ldsV1 : ldsV0;  // stage V(t+2) (after barrier)

        if (t < 30) STAGE_K((t + 2) * 64, kst);

        f32_4 sa[2][4] = {};
        QKT(kn, sa);        // tile t+1
        MASKF(t + 1, sa);
        PV(vc, pc);         // tile t (independent -> fills exp shadow)
        EXPW(sa, pn);       // tile t+1

        __syncthreads();    // staged K landed; all waves done reading vc/kn/pc
        if (t < 30) STAGE_V((t + 2) * 64, vst);
    }

    // ---- epilogue: PV(31) ----
    PV(ldsV1, ldsP1);

    // normalize + store: lsum[mt][r] is the row-sum for exactly the q-row
    // of[mt][jo][r] holds (col l15 copies are identical) -> no shuffles.
    const int hcol = (bh & 15) * 64;
#pragma unroll
    for (int mt = 0; mt < 2; ++mt)
#pragma unroll
        for (int r = 0; r < 4; ++r) {
            const float inv = 1.0f / fmaxf(lsum[mt][r], 1e-37f);
            const int qg = q0 + w * 32 + mt * 16 + quad * 4 + r;
#pragma unroll
            for (int jo = 0; jo < 4; ++jo)
                O[((size_t)b * SS + qg) * DD + hcol + jo * 16 + l15] =
                    (__bf16)(of[mt][jo][r] * inv);
        }
#undef STAGE_K
#undef STAGE_V
#undef QKT
#undef MASKF
#undef EXPW
#undef PV
}

// ---------------------------------------------------------------------------

extern "C" void kernel_launch(void* const* d_in, const int* in_sizes, int n_in,
                              void* d_out, int out_size, void* d_ws, size_t ws_size,
                              hipStream_t stream) {
    const float* xq   = (const float*)d_in[0];
    const float* xkv  = (const float*)d_in[1];
    const int*   mask = (const int*)d_in[2];
    const float* Wq   = (const float*)d_in[3];
    const float* bq   = (const float*)d_in[4];
    const float* Wk   = (const float*)d_in[5];
    const float* bk   = (const float*)d_in[6];
    const float* Wv   = (const float*)d_in[7];
    const float* bv   = (const float*)d_in[8];
    const float* Wo   = (const float*)d_in[9];
    const float* bo   = (const float*)d_in[10];

    __bf16* ws = (__bf16*)d_ws;
    const size_t big = (size_t)BB * SS * DD;  // 4,194,304
    const size_t wsz = (size_t)DD * DD;       // 1,048,576
    __bf16* Qw   = ws;
    __bf16* Kw   = Qw + big;
    __bf16* VTw  = Kw + big;
    __bf16* Aw   = VTw + big;
    __bf16* Xqb  = Aw + big;
    __bf16* Xkvb = Xqb + big;
    __bf16* Wqb  = Xkvb + big;
    __bf16* Wkb  = Wqb + wsz;
    __bf16* Wvb  = Wkb + wsz;
    __bf16* Wob  = Wvb + wsz;
    int* flags   = (int*)(Wob + wsz);  // 2048 ints

    conv_mask<<<dim3(4096, 8), dim3(256), 0, stream>>>(xq, xkv, Wq, Wk, Wv, Wo,
                                                       Xqb, Xkvb, Wqb, Wkb, Wvb, Wob,
                                                       mask, flags);
    gemm_qkv<<<dim3(32, 16, 3), dim3(256), 0, stream>>>(Xqb, Xkvb, Wqb, bq, Wkb, bk,
                                                        Wvb, bv, Qw, Kw, VTw);
    flash_attn<<<dim3(SS / 128, BB * NH), dim3(256), 0, stream>>>(Qw, Kw, VTw, mask,
                                                                  flags, Aw);
    gemm_final<<<dim3(32, 16), dim3(256), 0, stream>>>(Aw, Wob, bo, (float*)d_out);
}